// Round 1
// baseline (85.179 us; speedup 1.0000x reference)
//
#include <hip/hip_runtime.h>

#define Bsz 128
#define Csz 1024
#define Nsz 512
#define NCsz 1024
#define CAP 64   // max body literals per clause per sign; E[count]=10.2, P(>64) ~ 0

// ---------------- Kernel 1: fused preprocess ----------------
// blocks 0..767   : zero lbmax/ubmax (131072 u32) + gather mT (65536 f32)
// blocks 768..1023: wave-per-clause compaction of body literal lists + head extraction
__global__ __launch_bounds__(256) void k_pre(
    const float* __restrict__ preds,
    const float* __restrict__ pos_head, const float* __restrict__ neg_head,
    const float* __restrict__ pos_body, const float* __restrict__ neg_body,
    const int* __restrict__ atoms,
    float* __restrict__ mT, unsigned* __restrict__ lbmax, unsigned* __restrict__ ubmax,
    int* __restrict__ pos_list, int* __restrict__ neg_list,
    int* __restrict__ pos_cnt, int* __restrict__ neg_cnt,
    int* __restrict__ head_n, int* __restrict__ head_sign)
{
    int blk = blockIdx.x;
    if (blk < 768) {
        int t = blk * 256 + threadIdx.x;          // t in [0, 196608)
        if (t < 65536) {
            lbmax[t] = 0u;
        } else if (t < 131072) {
            ubmax[t - 65536] = 0u;
        } else {
            int g = t - 131072;                   // [0, 65536)
            int b = g >> 9, n = g & 511;          // n fast -> sorted-atom coalesced reads
            mT[n * Bsz + b] = preds[b * NCsz + atoms[n]];
        }
    } else {
        __shared__ int cnts[4][2];
        int wave = threadIdx.x >> 6, lane = threadIdx.x & 63;
        int c = (blk - 768) * 4 + wave;           // 256 blocks * 4 waves = 1024 clauses
        if (lane == 0) { cnts[wave][0] = 0; cnts[wave][1] = 0; }
        __syncthreads();
        const float* pbr = pos_body + c * Nsz;
        const float* nbr = neg_body + c * Nsz;
        const float* phr = pos_head + c * Nsz;
        const float* nhr = neg_head + c * Nsz;
        for (int k = 0; k < 8; k++) {
            int n = k * 64 + lane;
            if (pbr[n] != 0.f) { int s = atomicAdd(&cnts[wave][0], 1); if (s < CAP) pos_list[c * CAP + s] = n; }
            if (nbr[n] != 0.f) { int s = atomicAdd(&cnts[wave][1], 1); if (s < CAP) neg_list[c * CAP + s] = n; }
            if (phr[n] != 0.f) { head_n[c] = n; head_sign[c] = 1; }  // exactly one head per clause
            if (nhr[n] != 0.f) { head_n[c] = n; head_sign[c] = 0; }
        }
        if (lane == 0) {
            pos_cnt[c] = min(cnts[wave][0], CAP);
            neg_cnt[c] = min(cnts[wave][1], CAP);
        }
    }
}

// ---------------- Kernel 2: body_min + scatter-max into bounds ----------------
// One block per clause c, 128 threads = batch dim b.
// body_rev entries are 0 / (1-m) / m -> max reduction over the sparse lists, init 0.
// body_min in [0,1] (preds uniform [0,1)) -> float bits monotone -> uint atomicMax exact.
__global__ __launch_bounds__(128) void k_body(
    const float* __restrict__ mT,
    const int* __restrict__ pos_list, const int* __restrict__ neg_list,
    const int* __restrict__ pos_cnt, const int* __restrict__ neg_cnt,
    const int* __restrict__ head_n, const int* __restrict__ head_sign,
    unsigned* __restrict__ lbmax, unsigned* __restrict__ ubmax)
{
    int c = blockIdx.x, b = threadIdx.x;
    int pc = pos_cnt[c], ncnt = neg_cnt[c];
    const int* pl = pos_list + c * CAP;
    const int* nl = neg_list + c * CAP;
    float acc = 0.f;
    for (int e = 0; e < pc; e++)   acc = fmaxf(acc, 1.f - mT[pl[e] * Bsz + b]);
    for (int e = 0; e < ncnt; e++) acc = fmaxf(acc, mT[nl[e] * Bsz + b]);
    float bm = 1.f - acc;                          // body_min[b,c], >= 0
    unsigned* dst = head_sign[c] ? lbmax : ubmax;  // pos head -> lb, neg head -> ub
    atomicMax(dst + head_n[c] * Bsz + b, __float_as_uint(bm));  // coalesced across b
}

// ---------------- Kernel 3: clamp + scatter into output atom columns ----------------
// (non-atom columns already copied via d2d memcpy)
__global__ __launch_bounds__(256) void k_final(
    const float* __restrict__ mT,
    const unsigned* __restrict__ lbmax, const unsigned* __restrict__ ubmax,
    const int* __restrict__ atoms, float* __restrict__ out)
{
    int t = blockIdx.x * 256 + threadIdx.x;        // 65536 threads
    int b = t >> 9, n = t & 511;                   // n fast -> sorted-atom coalesced writes
    int i = n * Bsz + b;
    float m  = mT[i];
    float lb = __uint_as_float(lbmax[i]);
    float ub = 1.f - __uint_as_float(ubmax[i]);
    float lo = fminf(lb, ub), hi = fmaxf(lb, ub);
    out[b * NCsz + atoms[n]] = fmaxf(lo, fminf(hi, m));
}

extern "C" void kernel_launch(void* const* d_in, const int* in_sizes, int n_in,
                              void* d_out, int out_size, void* d_ws, size_t ws_size,
                              hipStream_t stream)
{
    const float* preds    = (const float*)d_in[0];
    const float* pos_head = (const float*)d_in[1];
    const float* neg_head = (const float*)d_in[2];
    const float* pos_body = (const float*)d_in[3];
    const float* neg_body = (const float*)d_in[4];
    const int*   atoms    = (const int*)d_in[5];
    float* out = (float*)d_out;

    char* ws = (char*)d_ws;
    float*    mT        = (float*)(ws);                       // 65536 f32  (mT[n][b])
    unsigned* lbmax     = (unsigned*)(ws + 65536u  * 4);      // 65536 u32  ([n][b])
    unsigned* ubmax     = (unsigned*)(ws + 131072u * 4);      // 65536 u32
    int*      pos_list  = (int*)(ws + 196608u * 4);           // C*CAP
    int*      neg_list  = (int*)(ws + 262144u * 4);           // C*CAP
    int*      pos_cnt   = (int*)(ws + 327680u * 4);           // C
    int*      neg_cnt   = pos_cnt + Csz;
    int*      head_n    = neg_cnt + Csz;
    int*      head_sign = head_n + Csz;                       // total ~1.30 MB

    // Non-atom columns pass through unchanged.
    hipMemcpyAsync(d_out, d_in[0], (size_t)Bsz * NCsz * sizeof(float),
                   hipMemcpyDeviceToDevice, stream);

    k_pre<<<1024, 256, 0, stream>>>(preds, pos_head, neg_head, pos_body, neg_body, atoms,
                                    mT, lbmax, ubmax, pos_list, neg_list,
                                    pos_cnt, neg_cnt, head_n, head_sign);

    k_body<<<Csz, Bsz, 0, stream>>>(mT, pos_list, neg_list, pos_cnt, neg_cnt,
                                    head_n, head_sign, lbmax, ubmax);

    k_final<<<(Bsz * Nsz) / 256, 256, 0, stream>>>(mT, lbmax, ubmax, atoms, out);
}